// Round 4
// baseline (237.920 us; speedup 1.0000x reference)
//
#include <hip/hip_runtime.h>

// IF neuron, multi-step, hard reset:
//   h_t = x_t + v_{t-1};  s_t = (h_t - 1.0 >= 0);  v_t = s_t ? 0 : h_t
//
// R3: R2 measured identical 86 us with VGPR=32 -> the compiler's
// pressure-minimizing scheduler sank every prefetch load to just before its
// use (MLP~1, latency-bound at ~3 TB/s L2-level). This round pins the
// software pipeline with __builtin_amdgcn_sched_barrier(0): loads for group
// g+1 are issued, then a full scheduling barrier, then group g is consumed
// and NT-stored. 8 loads in flight per wave in steady state.

typedef float v2f __attribute__((ext_vector_type(2)));

template <int T, int KB>
__global__ __launch_bounds__(256) void if_node_pipe_barrier(
    const float* __restrict__ x,    // (T, N)
    const float* __restrict__ v0,   // (N,)
    float* __restrict__ out,        // (T, N)
    long n2)                        // N/2
{
    long i = (long)blockIdx.x * blockDim.x + threadIdx.x;
    if (i >= n2) return;

    const v2f* __restrict__ x2 = (const v2f*)x;
    v2f*       __restrict__ o2 = (v2f*)out;

    v2f v = ((const v2f*)v0)[i];

    constexpr int G = T / KB;  // groups (4 for T=32, KB=8)
    v2f buf[2][KB];

    // Prologue: issue group 0's loads, then fence the schedule.
#pragma unroll
    for (int k = 0; k < KB; ++k)
        buf[0][k] = x2[(long)k * n2 + i];
    __builtin_amdgcn_sched_barrier(0);

#pragma unroll
    for (int g = 0; g < G; ++g) {
        const int cb = g & 1;
        // Issue next group's loads; barrier prevents the scheduler from
        // sinking them below the consume loop.
        if (g + 1 < G) {
#pragma unroll
            for (int k = 0; k < KB; ++k)
                buf[cb ^ 1][k] = x2[(long)((g + 1) * KB + k) * n2 + i];
            __builtin_amdgcn_sched_barrier(0);
        }
        // Consume current group.
#pragma unroll
        for (int k = 0; k < KB; ++k) {
            float hx = buf[cb][k].x + v.x;
            float hy = buf[cb][k].y + v.y;
            bool sx = (hx - 1.0f) >= 0.0f;
            bool sy = (hy - 1.0f) >= 0.0f;
            v2f s;
            s.x = sx ? 1.0f : 0.0f;
            s.y = sy ? 1.0f : 0.0f;
            v.x = sx ? 0.0f : hx;
            v.y = sy ? 0.0f : hy;
            __builtin_nontemporal_store(s, &o2[(long)(g * KB + k) * n2 + i]);
        }
        __builtin_amdgcn_sched_barrier(0);
    }
}

// Fallbacks for shapes the fast path doesn't cover.
__global__ __launch_bounds__(256) void if_node_f2_generic(
    const float* __restrict__ x, const float* __restrict__ v0,
    float* __restrict__ out, long n2, int T)
{
    long i = (long)blockIdx.x * blockDim.x + threadIdx.x;
    if (i >= n2) return;
    const v2f* x2 = (const v2f*)x;
    v2f*       o2 = (v2f*)out;
    v2f v = ((const v2f*)v0)[i];
    for (int t = 0; t < T; ++t) {
        v2f xv = x2[(long)t * n2 + i];
        float hx = xv.x + v.x;
        float hy = xv.y + v.y;
        bool sx = (hx - 1.0f) >= 0.0f;
        bool sy = (hy - 1.0f) >= 0.0f;
        v2f s;
        s.x = sx ? 1.0f : 0.0f;
        s.y = sy ? 1.0f : 0.0f;
        v.x = sx ? 0.0f : hx;
        v.y = sy ? 0.0f : hy;
        o2[(long)t * n2 + i] = s;
    }
}

__global__ __launch_bounds__(256) void if_node_scalar(
    const float* __restrict__ x, const float* __restrict__ v0,
    float* __restrict__ out, long n, int T)
{
    long i = (long)blockIdx.x * blockDim.x + threadIdx.x;
    if (i >= n) return;
    float v = v0[i];
    for (int t = 0; t < T; ++t) {
        float h = x[(long)t * n + i] + v;
        bool s = (h - 1.0f) >= 0.0f;
        out[(long)t * n + i] = s ? 1.0f : 0.0f;
        v = s ? 0.0f : h;
    }
}

extern "C" void kernel_launch(void* const* d_in, const int* in_sizes, int n_in,
                              void* d_out, int out_size, void* d_ws, size_t ws_size,
                              hipStream_t stream) {
    const float* x  = (const float*)d_in[0];   // (T, B, D) fp32
    const float* v0 = (const float*)d_in[1];   // (B, D) fp32
    float* out = (float*)d_out;                // (T, B, D) fp32

    long n = in_sizes[1];                      // B*D
    int  T = (int)(in_sizes[0] / n);           // 32

    int block = 256;
    if (T == 32 && (n & 1) == 0) {
        long n2 = n >> 1;
        long grid = (n2 + block - 1) / block;
        if_node_pipe_barrier<32, 8><<<dim3((unsigned)grid), dim3(block), 0, stream>>>(
            x, v0, out, n2);
    } else if ((n & 1) == 0) {
        long n2 = n >> 1;
        long grid = (n2 + block - 1) / block;
        if_node_f2_generic<<<dim3((unsigned)grid), dim3(block), 0, stream>>>(
            x, v0, out, n2, T);
    } else {
        long grid = (n + block - 1) / block;
        if_node_scalar<<<dim3((unsigned)grid), dim3(block), 0, stream>>>(
            x, v0, out, n, T);
    }
}

// Round 5
// 230.918 us; speedup vs baseline: 1.0303x; 1.0303x over previous
//
#include <hip/hip_runtime.h>

// IF neuron, multi-step, hard reset:
//   h_t = x_t + v_{t-1};  s_t = (h_t - 1.0 >= 0);  v_t = s_t ? 0 : h_t
//
// R4: R0/R2/R3 all pinned at ~86 us with ~8 KB/CU of loads in flight
// (latency-bound: 8 KB / ~667 ns = 12 GB/s/CU = 3 TB/s). Timestep
// prefetching failed twice: the loop-carried v dependency lets the
// scheduler sink loads to their use. This round forces MLP=4 through DATA
// FLOW: each thread owns 4 independent float2 columns (strided N/4), so the
// 4 loads per timestep are mutually independent and must all issue before
// the first s_waitcnt. 512 blocks -> 8 waves/CU -> ~16 KB/CU in flight,
// with trailing loads pipelined behind the first.

typedef float v2f __attribute__((ext_vector_type(2)));

template <int T, int C>
__global__ __launch_bounds__(256) void if_node_multicol(
    const float* __restrict__ x,    // (T, N)
    const float* __restrict__ v0,   // (N,)
    float* __restrict__ out,        // (T, N)
    long q)                         // column stride in float2 elems = (N/2)/C
{
    long i = (long)blockIdx.x * blockDim.x + threadIdx.x;
    if (i >= q) return;

    const v2f* __restrict__ x2 = (const v2f*)x;
    v2f*       __restrict__ o2 = (v2f*)out;
    const v2f* __restrict__ vv = (const v2f*)v0;

    const long n2 = q * C;

    v2f v[C];
#pragma unroll
    for (int c = 0; c < C; ++c)
        v[c] = vv[i + (long)c * q];

#pragma unroll
    for (int t = 0; t < T; ++t) {
        v2f xv[C];
        // C independent loads: all issue before the first wait (data flow).
#pragma unroll
        for (int c = 0; c < C; ++c)
            xv[c] = x2[(long)t * n2 + i + (long)c * q];
#pragma unroll
        for (int c = 0; c < C; ++c) {
            float hx = xv[c].x + v[c].x;
            float hy = xv[c].y + v[c].y;
            bool sx = (hx - 1.0f) >= 0.0f;
            bool sy = (hy - 1.0f) >= 0.0f;
            v2f s;
            s.x = sx ? 1.0f : 0.0f;
            s.y = sy ? 1.0f : 0.0f;
            v[c].x = sx ? 0.0f : hx;
            v[c].y = sy ? 0.0f : hy;
            __builtin_nontemporal_store(s, &o2[(long)t * n2 + i + (long)c * q]);
        }
    }
}

// Fallbacks for shapes the fast path doesn't cover.
__global__ __launch_bounds__(256) void if_node_f2_generic(
    const float* __restrict__ x, const float* __restrict__ v0,
    float* __restrict__ out, long n2, int T)
{
    long i = (long)blockIdx.x * blockDim.x + threadIdx.x;
    if (i >= n2) return;
    const v2f* x2 = (const v2f*)x;
    v2f*       o2 = (v2f*)out;
    v2f v = ((const v2f*)v0)[i];
    for (int t = 0; t < T; ++t) {
        v2f xv = x2[(long)t * n2 + i];
        float hx = xv.x + v.x;
        float hy = xv.y + v.y;
        bool sx = (hx - 1.0f) >= 0.0f;
        bool sy = (hy - 1.0f) >= 0.0f;
        v2f s;
        s.x = sx ? 1.0f : 0.0f;
        s.y = sy ? 1.0f : 0.0f;
        v.x = sx ? 0.0f : hx;
        v.y = sy ? 0.0f : hy;
        o2[(long)t * n2 + i] = s;
    }
}

__global__ __launch_bounds__(256) void if_node_scalar(
    const float* __restrict__ x, const float* __restrict__ v0,
    float* __restrict__ out, long n, int T)
{
    long i = (long)blockIdx.x * blockDim.x + threadIdx.x;
    if (i >= n) return;
    float v = v0[i];
    for (int t = 0; t < T; ++t) {
        float h = x[(long)t * n + i] + v;
        bool s = (h - 1.0f) >= 0.0f;
        out[(long)t * n + i] = s ? 1.0f : 0.0f;
        v = s ? 0.0f : h;
    }
}

extern "C" void kernel_launch(void* const* d_in, const int* in_sizes, int n_in,
                              void* d_out, int out_size, void* d_ws, size_t ws_size,
                              hipStream_t stream) {
    const float* x  = (const float*)d_in[0];   // (T, B, D) fp32
    const float* v0 = (const float*)d_in[1];   // (B, D) fp32
    float* out = (float*)d_out;                // (T, B, D) fp32

    long n = in_sizes[1];                      // B*D
    int  T = (int)(in_sizes[0] / n);           // 32

    int block = 256;
    constexpr int C = 4;
    if (T == 32 && (n % (2 * C)) == 0) {
        long n2 = n >> 1;          // float2 elements
        long q  = n2 / C;          // per-column float2 elements
        long grid = (q + block - 1) / block;
        if_node_multicol<32, C><<<dim3((unsigned)grid), dim3(block), 0, stream>>>(
            x, v0, out, q);
    } else if ((n & 1) == 0) {
        long n2 = n >> 1;
        long grid = (n2 + block - 1) / block;
        if_node_f2_generic<<<dim3((unsigned)grid), dim3(block), 0, stream>>>(
            x, v0, out, n2, T);
    } else {
        long grid = (n + block - 1) / block;
        if_node_scalar<<<dim3((unsigned)grid), dim3(block), 0, stream>>>(
            x, v0, out, n, T);
    }
}

// Round 6
// 230.731 us; speedup vs baseline: 1.0312x; 1.0008x over previous
//
#include <hip/hip_runtime.h>

// IF neuron, multi-step, hard reset:
//   h_t = x_t + v_{t-1};  s_t = (h_t - 1.0 >= 0);  v_t = s_t ? 0 : h_t
//
// R6: device-wide in-flight load bytes are capped at one t-slice (4 MiB =
// 16 KB/CU) unless we prefetch ACROSS t. R4 (C=4 independent columns,
// MLP=4 by data flow) got ~74 us. This round adds a 3-slot rotating
// t-prefetch (t+1, t+2 issued before consuming t) on top of the C=4
// columns: 8-12 loads in flight per wave at the consume point
// (32-48 KB/CU), sched_barrier(0) pinning issue order. Stores remain
// non-temporal fire-and-forget.

typedef float v2f __attribute__((ext_vector_type(2)));

template <int T, int C>
__global__ __launch_bounds__(256) void if_node_mc_pf2(
    const float* __restrict__ x,    // (T, N)
    const float* __restrict__ v0,   // (N,)
    float* __restrict__ out,        // (T, N)
    long q)                         // column stride in float2 elems = (N/2)/C
{
    long i = (long)blockIdx.x * blockDim.x + threadIdx.x;
    if (i >= q) return;

    const v2f* __restrict__ x2 = (const v2f*)x;
    v2f*       __restrict__ o2 = (v2f*)out;
    const v2f* __restrict__ vv = (const v2f*)v0;

    const long n2 = q * C;

    v2f v[C];
#pragma unroll
    for (int c = 0; c < C; ++c)
        v[c] = vv[i + (long)c * q];

    // 3-slot rotating buffer over timesteps.
    v2f buf[3][C];

#pragma unroll
    for (int c = 0; c < C; ++c)
        buf[0][c] = x2[(long)0 * n2 + i + (long)c * q];
#pragma unroll
    for (int c = 0; c < C; ++c)
        buf[1][c] = x2[(long)1 * n2 + i + (long)c * q];
    __builtin_amdgcn_sched_barrier(0);

#pragma unroll
    for (int t = 0; t < T; ++t) {
        // Issue loads for t+2 before consuming t (addresses independent of v).
        if (t + 2 < T) {
            const int ps = (t + 2) % 3;
#pragma unroll
            for (int c = 0; c < C; ++c)
                buf[ps][c] = x2[(long)(t + 2) * n2 + i + (long)c * q];
        }
        __builtin_amdgcn_sched_barrier(0);

        const int cs = t % 3;
#pragma unroll
        for (int c = 0; c < C; ++c) {
            float hx = buf[cs][c].x + v[c].x;
            float hy = buf[cs][c].y + v[c].y;
            bool sx = (hx - 1.0f) >= 0.0f;
            bool sy = (hy - 1.0f) >= 0.0f;
            v2f s;
            s.x = sx ? 1.0f : 0.0f;
            s.y = sy ? 1.0f : 0.0f;
            v[c].x = sx ? 0.0f : hx;
            v[c].y = sy ? 0.0f : hy;
            __builtin_nontemporal_store(s, &o2[(long)t * n2 + i + (long)c * q]);
        }
        __builtin_amdgcn_sched_barrier(0);
    }
}

// Fallbacks for shapes the fast path doesn't cover.
__global__ __launch_bounds__(256) void if_node_f2_generic(
    const float* __restrict__ x, const float* __restrict__ v0,
    float* __restrict__ out, long n2, int T)
{
    long i = (long)blockIdx.x * blockDim.x + threadIdx.x;
    if (i >= n2) return;
    const v2f* x2 = (const v2f*)x;
    v2f*       o2 = (v2f*)out;
    v2f v = ((const v2f*)v0)[i];
    for (int t = 0; t < T; ++t) {
        v2f xv = x2[(long)t * n2 + i];
        float hx = xv.x + v.x;
        float hy = xv.y + v.y;
        bool sx = (hx - 1.0f) >= 0.0f;
        bool sy = (hy - 1.0f) >= 0.0f;
        v2f s;
        s.x = sx ? 1.0f : 0.0f;
        s.y = sy ? 1.0f : 0.0f;
        v.x = sx ? 0.0f : hx;
        v.y = sy ? 0.0f : hy;
        o2[(long)t * n2 + i] = s;
    }
}

__global__ __launch_bounds__(256) void if_node_scalar(
    const float* __restrict__ x, const float* __restrict__ v0,
    float* __restrict__ out, long n, int T)
{
    long i = (long)blockIdx.x * blockDim.x + threadIdx.x;
    if (i >= n) return;
    float v = v0[i];
    for (int t = 0; t < T; ++t) {
        float h = x[(long)t * n + i] + v;
        bool s = (h - 1.0f) >= 0.0f;
        out[(long)t * n + i] = s ? 1.0f : 0.0f;
        v = s ? 0.0f : h;
    }
}

extern "C" void kernel_launch(void* const* d_in, const int* in_sizes, int n_in,
                              void* d_out, int out_size, void* d_ws, size_t ws_size,
                              hipStream_t stream) {
    const float* x  = (const float*)d_in[0];   // (T, B, D) fp32
    const float* v0 = (const float*)d_in[1];   // (B, D) fp32
    float* out = (float*)d_out;                // (T, B, D) fp32

    long n = in_sizes[1];                      // B*D
    int  T = (int)(in_sizes[0] / n);           // 32

    int block = 256;
    constexpr int C = 4;
    if (T == 32 && (n % (2 * C)) == 0) {
        long n2 = n >> 1;          // float2 elements
        long q  = n2 / C;          // per-column float2 elements
        long grid = (q + block - 1) / block;
        if_node_mc_pf2<32, C><<<dim3((unsigned)grid), dim3(block), 0, stream>>>(
            x, v0, out, q);
    } else if ((n & 1) == 0) {
        long n2 = n >> 1;
        long grid = (n2 + block - 1) / block;
        if_node_f2_generic<<<dim3((unsigned)grid), dim3(block), 0, stream>>>(
            x, v0, out, n2, T);
    } else {
        long grid = (n + block - 1) / block;
        if_node_scalar<<<dim3((unsigned)grid), dim3(block), 0, stream>>>(
            x, v0, out, n, T);
    }
}